// Round 2
// baseline (168.158 us; speedup 1.0000x reference)
//
#include <hip/hip_runtime.h>
#include <math.h>

// S4 layer: B=16, S=4096, D=256, N=16, then LayerNorm over D.
//   A_d = exp(-DT*|A|), v_t = DT*(Bm @ u_t)
//   h_t = clip(A_d*h_{t-1} + v_t); y_t = clip(h_t @ Cm^T + u_t*Dv); out = LN(y)
// Chunked linear scan (chunks of 64 tokens), 2 dispatches:
//   k_carry: per (b,chunk): v (store to ws) + chunk carry  [reads x 64 MiB]
//   k_out:   per (b,chunk): Hstart from carries (redundant weighted sum),
//            Kogge-Stone weighted scan in LDS, y + LayerNorm, store.
// B-matvec reads Bm rows directly via wave-uniform addrs (scalar s_load pipe),
// DT folded into one post-scale -> no transpose kernel needed.

#define NB 16
#define NS 4096
#define ND 256
#define NN 16
#define NL 64
#define NCH 64 // NS / NL
#define DTC 1e-4f
#define XSTR 129 // x half-tile LDS row stride (128 + 1 pad -> <=2-way banks, free)
#define P2STR 17 // partial-v LDS stride
#define SCSTR 20 // scan LDS stride (80B rows, 16B-aligned for b128 broadcast reads)
#define P64STR 17
#define NPOW (NL + 1)

__device__ __forceinline__ float clip10(float v) { return fminf(fmaxf(v, -10.f), 10.f); }

// Ptab[n][k] = A_d[n]^k for k = 0..64
__device__ __forceinline__ void build_ptab(const float* __restrict__ A, float* Ptab, int tid) {
  if (tid < NN) {
    float ad = expf(-DTC * fabsf(A[tid]));
    float p = 1.f;
    for (int k = 0; k < NPOW; ++k) { Ptab[tid * NPOW + k] = p; p *= ad; }
  }
}

__global__ __launch_bounds__(256, 2) void k_carry(const float* __restrict__ x,
                                                  const float* __restrict__ A,
                                                  const float* __restrict__ Bm,
                                                  float* __restrict__ carry,
                                                  float* __restrict__ vws) {
  __shared__ __align__(16) float xt[NL * XSTR];
  __shared__ __align__(16) float part2[4 * NL * P2STR];
  __shared__ float Ptab[NN * NPOW];
  __shared__ float part3[4][NN];
  const int tid = threadIdx.x;
  const int blk = blockIdx.x;
  const int b = blk >> 6, c = blk & 63;

  build_ptab(A, Ptab, tid);
  const int t = tid & 63;
  const int dq = __builtin_amdgcn_readfirstlane(tid >> 6); // wave id -> SGPR
  float acc[NN];
#pragma unroll
  for (int n = 0; n < NN; ++n) acc[n] = 0.f;

  const float* xg = x + ((size_t)(b * NS + c * NL)) * ND;
  for (int h = 0; h < 2; ++h) {
    __syncthreads(); // protect xt from previous half's readers
    const float4* src4 = (const float4*)(xg + 128 * h);
#pragma unroll
    for (int k = 0; k < 8; ++k) {
      int fi4 = tid + 256 * k; // 2048 float4 = 64 rows x 128 floats
      int r = fi4 >> 5, q = fi4 & 31;
      float4 val = src4[r * 64 + q]; // global row stride = 64 float4
      float* dst = xt + r * XSTR + 4 * q;
      dst[0] = val.x; dst[1] = val.y; dst[2] = val.z; dst[3] = val.w;
    }
    __syncthreads();
    const int dl0 = 32 * dq;
    float xr[32]; // this thread's token-row segment, hoisted to VGPRs
#pragma unroll
    for (int j = 0; j < 32; ++j) xr[j] = xt[t * XSTR + dl0 + j]; // 2-way banks: free
    const float* bbase = Bm + 128 * h + dl0; // wave-uniform -> scalar loads
#pragma unroll
    for (int n = 0; n < NN; ++n) {
      const float* bp = bbase + n * ND; // s_load_dwordx16 x2 territory
#pragma unroll
      for (int j = 0; j < 32; ++j) acc[n] = fmaf(xr[j], bp[j], acc[n]);
    }
  }

  { // cross-wave (dq) reduction of v partials; fold DT here
    float* pp = part2 + dq * (NL * P2STR) + t * P2STR;
#pragma unroll
    for (int n = 0; n < NN; ++n) pp[n] = acc[n] * DTC;
  }
  __syncthreads();
  float v4[4];
#pragma unroll
  for (int k = 0; k < 4; ++k) { // e = tid+256k <-> (t = e>>4, n = e&15)
    int e = tid + 256 * k;
    int o = (e >> 4) * P2STR + (e & 15);
    v4[k] = (part2[o] + part2[NL * P2STR + o]) +
            (part2[2 * NL * P2STR + o] + part2[3 * NL * P2STR + o]);
  }
  float* vp = vws + (size_t)blk * (NL * NN);
#pragma unroll
  for (int k = 0; k < 4; ++k) vp[tid + 256 * k] = v4[k];

  // carry[n] = sum_t A^(63-t) * v[t][n]
  const int t0 = tid >> 4, n = tid & 15;
  float val = 0.f;
#pragma unroll
  for (int k = 0; k < 4; ++k)
    val = fmaf(Ptab[n * NPOW + 63 - (t0 + 16 * k)], v4[k], val);
  val += __shfl_xor(val, 16);
  val += __shfl_xor(val, 32);
  const int w = tid >> 6, lane = tid & 63;
  if (lane < NN) part3[w][lane] = val;
  __syncthreads();
  if (tid < NN)
    carry[(size_t)(b * NCH + c) * NN + tid] =
        (part3[0][tid] + part3[1][tid]) + (part3[2][tid] + part3[3][tid]);
}

__global__ __launch_bounds__(256, 2) void k_out(const float* __restrict__ x,
                                                const float* __restrict__ A,
                                                const float* __restrict__ Cm,
                                                const float* __restrict__ Dv,
                                                const float* __restrict__ gamma,
                                                const float* __restrict__ beta,
                                                const float* __restrict__ carry,
                                                const float* __restrict__ vws,
                                                float* __restrict__ out) {
  __shared__ __align__(16) float scan[NL * SCSTR];
  __shared__ float Ptab[NN * NPOW];
  __shared__ float P64[NL * P64STR]; // [k][n], a64^k
  __shared__ float hst[NN];
  __shared__ float part3[4][NN];
  const int tid = threadIdx.x;
  const int blk = blockIdx.x;
  const int b = blk >> 6, c = blk & 63;

  build_ptab(A, Ptab, tid);
  const float* vp = vws + (size_t)blk * (NL * NN);
#pragma unroll
  for (int k = 0; k < 4; ++k) {
    int e = tid + 256 * k;
    scan[(e >> 4) * SCSTR + (e & 15)] = vp[e];
  }
  __syncthreads(); // Ptab + scan ready

  if (tid < NN) { // P64[k][n] = (A_d[n]^64)^k
    float a64 = Ptab[tid * NPOW + NL];
    float p = 1.f;
    for (int k = 0; k < NL; ++k) { P64[k * P64STR + tid] = p; p *= a64; }
  }
  __syncthreads();

  // Hstart[n] = sum_{c'<c} a64^(c-1-c') * carry[b][c'][n]  (state entering chunk c)
  {
    const int tt = tid >> 4, n = tid & 15;
    const float* cp = carry + (size_t)b * (NCH * NN);
    float val = 0.f;
#pragma unroll
    for (int q = 0; q < 4; ++q) {
      int cc = tt + 16 * q;
      if (cc < c) val = fmaf(P64[(c - 1 - cc) * P64STR + n], cp[cc * NN + n], val);
    }
    val += __shfl_xor(val, 16);
    val += __shfl_xor(val, 32);
    const int w = tid >> 6, lane = tid & 63;
    if (lane < NN) part3[w][lane] = val;
  }
  __syncthreads();
  if (tid < NN)
    hst[tid] = (part3[0][tid] + part3[1][tid]) + (part3[2][tid] + part3[3][tid]);

  // Kogge-Stone inclusive scan over t (per n) with decay weights A^s
#pragma unroll
  for (int s = 1; s <= 32; s <<= 1) {
    float tmp[4];
#pragma unroll
    for (int k = 0; k < 4; ++k) {
      int e = tid + 256 * k;
      int tt = e >> 4, n = e & 15;
      tmp[k] = (tt >= s) ? Ptab[n * NPOW + s] * scan[(tt - s) * SCSTR + n] : 0.f;
    }
    __syncthreads();
#pragma unroll
    for (int k = 0; k < 4; ++k) {
      int e = tid + 256 * k;
      scan[(e >> 4) * SCSTR + (e & 15)] += tmp[k];
    }
    __syncthreads();
  }
  // h_t = A^(tl+1) * Hstart + hloc_t, clip (no-op on this data, matches ref)
#pragma unroll
  for (int k = 0; k < 4; ++k) {
    int e = tid + 256 * k;
    int tt = e >> 4, n = e & 15;
    float hv = fmaf(Ptab[n * NPOW + tt + 1], hst[n], scan[tt * SCSTR + n]);
    scan[tt * SCSTR + n] = clip10(hv);
  }
  __syncthreads();

  // y = h @ Cm^T + u*Dv, clip, LayerNorm over d (d = lane dim -> wave butterfly)
  const int l = tid & 63;
  const int w = __builtin_amdgcn_readfirstlane(tid >> 6);
  float cm[4][NN]; // Cm rows for this lane's 4 d's, hoisted
  const float4* Cm4 = (const float4*)Cm;
#pragma unroll
  for (int j = 0; j < 4; ++j)
#pragma unroll
    for (int q = 0; q < 4; ++q) {
      float4 cv = Cm4[(4 * l + j) * 4 + q];
      cm[j][4 * q + 0] = cv.x; cm[j][4 * q + 1] = cv.y;
      cm[j][4 * q + 2] = cv.z; cm[j][4 * q + 3] = cv.w;
    }
  const float4 dv = ((const float4*)Dv)[l];
  const float4 gm = ((const float4*)gamma)[l];
  const float4 bet = ((const float4*)beta)[l];
  const size_t rowbase = ((size_t)(b * NS + c * NL)) * ND;
  const float* xbase = x + rowbase + 4 * l;

  float4 xv = *(const float4*)(xbase + (size_t)(16 * w) * ND); // prefetch t=16w
#pragma unroll 1
  for (int it = 0; it < 16; ++it) { // wave w handles tokens [16w, 16w+16)
    const int t = 16 * w + it;
    const int tn = (it < 15) ? (t + 1) : t;
    float4 xn = *(const float4*)(xbase + (size_t)tn * ND); // prefetch next token
    const float* hrow = scan + t * SCSTR; // 16B-aligned, broadcast b128 reads
    float y0 = xv.x * dv.x, y1 = xv.y * dv.y, y2 = xv.z * dv.z, y3 = xv.w * dv.w;
#pragma unroll
    for (int nn = 0; nn < NN; ++nn) {
      float hv = hrow[nn];
      y0 = fmaf(hv, cm[0][nn], y0);
      y1 = fmaf(hv, cm[1][nn], y1);
      y2 = fmaf(hv, cm[2][nn], y2);
      y3 = fmaf(hv, cm[3][nn], y3);
    }
    y0 = clip10(y0); y1 = clip10(y1); y2 = clip10(y2); y3 = clip10(y3);
    float s1 = (y0 + y1) + (y2 + y3);
    float s2 = fmaf(y0, y0, fmaf(y1, y1, fmaf(y2, y2, y3 * y3)));
#pragma unroll
    for (int off = 32; off; off >>= 1) {
      s1 += __shfl_xor(s1, off);
      s2 += __shfl_xor(s2, off);
    }
    const float mu = s1 * (1.f / 256.f);
    const float var = fmaf(-mu, mu, s2 * (1.f / 256.f));
    const float rs = rsqrtf(var + 1e-5f);
    float4 o;
    o.x = fmaf((y0 - mu) * rs, gm.x, bet.x);
    o.y = fmaf((y1 - mu) * rs, gm.y, bet.y);
    o.z = fmaf((y2 - mu) * rs, gm.z, bet.z);
    o.w = fmaf((y3 - mu) * rs, gm.w, bet.w);
    *(float4*)(out + rowbase + (size_t)t * ND + 4 * l) = o;
    xv = xn;
  }
}

extern "C" void kernel_launch(void* const* d_in, const int* in_sizes, int n_in,
                              void* d_out, int out_size, void* d_ws, size_t ws_size,
                              hipStream_t stream) {
  const float* x = (const float*)d_in[0];
  const float* A = (const float*)d_in[1];
  const float* Bm = (const float*)d_in[2];
  const float* Cm = (const float*)d_in[3];
  const float* Dv = (const float*)d_in[4];
  const float* gamma = (const float*)d_in[5];
  const float* beta = (const float*)d_in[6];
  float* out = (float*)d_out;
  char* ws = (char*)d_ws;

  float* carry = (float*)ws;            // 64 KiB
  float* vws = (float*)(ws + 65536);    // 4 MiB (ws_size observed 256 MiB)

  k_carry<<<dim3(NB * NCH), dim3(256), 0, stream>>>(x, A, Bm, carry, vws);
  k_out<<<dim3(NB * NCH), dim3(256), 0, stream>>>(x, A, Cm, Dv, gamma, beta,
                                                  carry, vws, out);
}

// Round 4
// 153.961 us; speedup vs baseline: 1.0922x; 1.0922x over previous
//
#include <hip/hip_runtime.h>
#include <math.h>

// S4 layer: B=16, S=4096, D=256, N=16, then LayerNorm over D.
//   A_d = exp(-DT*|A|), v_t = DT*(Bm @ u_t)
//   h_t = clip(A_d*h_{t-1} + v_t); y_t = clip(h_t @ Cm^T + u_t*Dv); out = LN(y)
// Chunked linear scan (chunks of 64 tokens), 2 dispatches:
//   k_carry: per (b,chunk): v (store to ws) + chunk carry  [reads x 64 MiB]
//   k_out:   per (b,chunk): Hstart from carries (redundant weighted sum),
//            Kogge-Stone weighted scan in LDS, y + LayerNorm, store.
// R3: B staged in LDS [d][n]-major -> wave-uniform ds_read_b128 broadcasts in
// the FMA loop (kills the R2 s_load/lgkmcnt serialization); part2 aliased onto
// xt; Ptab/P64 tables replaced by direct expf -> 3 blocks/CU for k_carry.
// R4: fix nontemporal store (needs native vector type, not HIP_vector_type).

#define NB 16
#define NS 4096
#define ND 256
#define NN 16
#define NL 64
#define NCH 64 // NS / NL
#define DTC 1e-4f
#define XSTR 129 // x half-tile LDS row stride (odd -> b32 reads 2-way, free)
#define P2STR 17 // partial-v LDS stride
#define SCSTR 20 // scan LDS stride (80B rows, 16B-aligned for b128 broadcast)
#define NPOW (NL + 1)

typedef float f32x4 __attribute__((ext_vector_type(4)));

__device__ __forceinline__ float clip10(float v) { return fminf(fmaxf(v, -10.f), 10.f); }

__global__ __launch_bounds__(256, 3) void k_carry(const float* __restrict__ x,
                                                  const float* __restrict__ A,
                                                  const float* __restrict__ Bm,
                                                  float* __restrict__ carry,
                                                  float* __restrict__ vws) {
  __shared__ __align__(16) float btl[ND * NN];   // 16 KB: DT*Bm, [d][n]-major
  __shared__ __align__(16) float xt[NL * XSTR];  // 33 KB; reused as part2 later
  __shared__ float part3[4][NN];
  const int tid = threadIdx.x;
  const int blk = blockIdx.x;
  const int b = blk >> 6, c = blk & 63;

  // Stage DT*Bm transposed to [d][n]. Gather reads (L2-hot, once per block),
  // linear conflict-free LDS writes; rows 64B-aligned -> b128 broadcast reads.
#pragma unroll
  for (int k = 0; k < 16; ++k) {
    int i = tid + 256 * k; // i = d*16 + n
    btl[i] = DTC * Bm[(i & 15) * ND + (i >> 4)];
  }

  const int t = tid & 63;
  const int dq = __builtin_amdgcn_readfirstlane(tid >> 6); // wave id
  float acc[NN];
#pragma unroll
  for (int n = 0; n < NN; ++n) acc[n] = 0.f;

  const float* xg = x + ((size_t)(b * NS + c * NL)) * ND;
  for (int h = 0; h < 2; ++h) {
    __syncthreads(); // protect xt (and btl on h=0) from earlier phase
    const float4* src4 = (const float4*)(xg + 128 * h);
#pragma unroll
    for (int k = 0; k < 8; ++k) {
      int fi4 = tid + 256 * k; // 2048 float4 = 64 rows x 128 floats
      int r = fi4 >> 5, q = fi4 & 31;
      float4 val = src4[r * 64 + q]; // full-line coalesced (global stride 64 f4)
      float* dst = xt + r * XSTR + 4 * q;
      dst[0] = val.x; dst[1] = val.y; dst[2] = val.z; dst[3] = val.w;
    }
    __syncthreads();
    const int dl0 = 32 * dq;
    const float* xrow = xt + t * XSTR + dl0;
    const float* brow = btl + (128 * h + dl0) * NN;
#pragma unroll 4
    for (int j = 0; j < 32; ++j) {
      float u = xrow[j];               // banks (t+j)%32: 2-way, free
      const float* bp = brow + j * NN; // wave-uniform -> 4x ds_read_b128 bcast
#pragma unroll
      for (int n = 0; n < NN; ++n) acc[n] = fmaf(u, bp[n], acc[n]);
    }
  }

  __syncthreads(); // all xt reads done -> safe to alias part2 onto xt
  float* part2 = xt;
  {
    float* pp = part2 + dq * (NL * P2STR) + t * P2STR;
#pragma unroll
    for (int n = 0; n < NN; ++n) pp[n] = acc[n];
  }
  __syncthreads();
  float v4[4];
#pragma unroll
  for (int k = 0; k < 4; ++k) { // e = tid+256k <-> (t = e>>4, n = e&15)
    int e = tid + 256 * k;
    int o = (e >> 4) * P2STR + (e & 15);
    v4[k] = (part2[o] + part2[NL * P2STR + o]) +
            (part2[2 * NL * P2STR + o] + part2[3 * NL * P2STR + o]);
  }
  float* vp = vws + (size_t)blk * (NL * NN);
#pragma unroll
  for (int k = 0; k < 4; ++k) vp[tid + 256 * k] = v4[k];

  // carry[n] = sum_t A_d[n]^(63-t) * v[t][n]; weights via expf (no table)
  const int t0 = tid >> 4, n = tid & 15;
  const float pn = DTC * fabsf(A[n]);
  float val = 0.f;
#pragma unroll
  for (int k = 0; k < 4; ++k)
    val = fmaf(expf(-pn * (float)(63 - t0 - 16 * k)), v4[k], val);
  val += __shfl_xor(val, 16);
  val += __shfl_xor(val, 32);
  const int w = tid >> 6, lane = tid & 63;
  if (lane < NN) part3[w][lane] = val;
  __syncthreads();
  if (tid < NN)
    carry[(size_t)(b * NCH + c) * NN + tid] =
        (part3[0][tid] + part3[1][tid]) + (part3[2][tid] + part3[3][tid]);
}

__global__ __launch_bounds__(256, 4) void k_out(const float* __restrict__ x,
                                                const float* __restrict__ A,
                                                const float* __restrict__ Cm,
                                                const float* __restrict__ Dv,
                                                const float* __restrict__ gamma,
                                                const float* __restrict__ beta,
                                                const float* __restrict__ carry,
                                                const float* __restrict__ vws,
                                                float* __restrict__ out) {
  __shared__ __align__(16) float scan[NL * SCSTR];
  __shared__ float Ptab[NN * NPOW]; // Ptab[n][k] = A_d[n]^k
  __shared__ float hst[NN];
  __shared__ float part3[4][NN];
  const int tid = threadIdx.x;
  const int blk = blockIdx.x;
  const int b = blk >> 6, c = blk & 63;

  if (tid < NN) {
    float ad = expf(-DTC * fabsf(A[tid]));
    float p = 1.f;
    for (int k = 0; k < NPOW; ++k) { Ptab[tid * NPOW + k] = p; p *= ad; }
  }
  const float* vp = vws + (size_t)blk * (NL * NN);
#pragma unroll
  for (int k = 0; k < 4; ++k) {
    int e = tid + 256 * k;
    scan[(e >> 4) * SCSTR + (e & 15)] = vp[e];
  }

  // Hstart[n] = sum_{c'<c} (A_d^64)^(c-1-c') * carry[b][c'][n], weights by expf
  {
    const int tt = tid >> 4, n = tid & 15;
    const float pn64 = 64.f * DTC * fabsf(A[n]);
    const float* cp = carry + (size_t)b * (NCH * NN);
    float val = 0.f;
#pragma unroll
    for (int q = 0; q < 4; ++q) {
      int cc = tt + 16 * q;
      if (cc < c) val = fmaf(expf(-pn64 * (float)(c - 1 - cc)), cp[cc * NN + n], val);
    }
    val += __shfl_xor(val, 16);
    val += __shfl_xor(val, 32);
    const int w = tid >> 6, lane = tid & 63;
    if (lane < NN) part3[w][lane] = val;
  }
  __syncthreads(); // scan + Ptab + part3 ready
  if (tid < NN)
    hst[tid] = (part3[0][tid] + part3[1][tid]) + (part3[2][tid] + part3[3][tid]);
  __syncthreads();

  // Kogge-Stone inclusive scan over t (per n) with decay weights A^s
#pragma unroll
  for (int s = 1; s <= 32; s <<= 1) {
    float tmp[4];
#pragma unroll
    for (int k = 0; k < 4; ++k) {
      int e = tid + 256 * k;
      int tt = e >> 4, n = e & 15;
      tmp[k] = (tt >= s) ? Ptab[n * NPOW + s] * scan[(tt - s) * SCSTR + n] : 0.f;
    }
    __syncthreads();
#pragma unroll
    for (int k = 0; k < 4; ++k) {
      int e = tid + 256 * k;
      scan[(e >> 4) * SCSTR + (e & 15)] += tmp[k];
    }
    __syncthreads();
  }
  // h_t = A^(tl+1) * Hstart + hloc_t, clip (no-op on this data, matches ref)
#pragma unroll
  for (int k = 0; k < 4; ++k) {
    int e = tid + 256 * k;
    int tt = e >> 4, n = e & 15;
    float hv = fmaf(Ptab[n * NPOW + tt + 1], hst[n], scan[tt * SCSTR + n]);
    scan[tt * SCSTR + n] = clip10(hv);
  }
  __syncthreads();

  // y = h @ Cm^T + u*Dv, clip, LayerNorm over d (d = lane dim -> wave butterfly)
  const int l = tid & 63;
  const int w = __builtin_amdgcn_readfirstlane(tid >> 6);
  float cm[4][NN]; // Cm rows for this lane's 4 d's, hoisted
  const float4* Cm4 = (const float4*)Cm;
#pragma unroll
  for (int j = 0; j < 4; ++j)
#pragma unroll
    for (int q = 0; q < 4; ++q) {
      float4 cv = Cm4[(4 * l + j) * 4 + q];
      cm[j][4 * q + 0] = cv.x; cm[j][4 * q + 1] = cv.y;
      cm[j][4 * q + 2] = cv.z; cm[j][4 * q + 3] = cv.w;
    }
  const float4 dv = ((const float4*)Dv)[l];
  const float4 gm = ((const float4*)gamma)[l];
  const float4 bet = ((const float4*)beta)[l];
  const size_t rowbase = ((size_t)(b * NS + c * NL)) * ND;
  const float* xbase = x + rowbase + 4 * l;

  float4 xv = *(const float4*)(xbase + (size_t)(16 * w) * ND); // prefetch t=16w
#pragma unroll 1
  for (int it = 0; it < 16; ++it) { // wave w handles tokens [16w, 16w+16)
    const int t = 16 * w + it;
    const int tn = (it < 15) ? (t + 1) : t;
    float4 xn = *(const float4*)(xbase + (size_t)tn * ND); // prefetch next token
    const float* hrow = scan + t * SCSTR; // 16B-aligned uniform b128 broadcasts
    float y0 = xv.x * dv.x, y1 = xv.y * dv.y, y2 = xv.z * dv.z, y3 = xv.w * dv.w;
#pragma unroll
    for (int nn = 0; nn < NN; ++nn) {
      float hv = hrow[nn];
      y0 = fmaf(hv, cm[0][nn], y0);
      y1 = fmaf(hv, cm[1][nn], y1);
      y2 = fmaf(hv, cm[2][nn], y2);
      y3 = fmaf(hv, cm[3][nn], y3);
    }
    y0 = clip10(y0); y1 = clip10(y1); y2 = clip10(y2); y3 = clip10(y3);
    float s1 = (y0 + y1) + (y2 + y3);
    float s2 = fmaf(y0, y0, fmaf(y1, y1, fmaf(y2, y2, y3 * y3)));
#pragma unroll
    for (int off = 32; off; off >>= 1) {
      s1 += __shfl_xor(s1, off);
      s2 += __shfl_xor(s2, off);
    }
    const float mu = s1 * (1.f / 256.f);
    const float var = fmaf(-mu, mu, s2 * (1.f / 256.f));
    const float rs = rsqrtf(var + 1e-5f);
    f32x4 o;
    o.x = fmaf((y0 - mu) * rs, gm.x, bet.x);
    o.y = fmaf((y1 - mu) * rs, gm.y, bet.y);
    o.z = fmaf((y2 - mu) * rs, gm.z, bet.z);
    o.w = fmaf((y3 - mu) * rs, gm.w, bet.w);
    // nontemporal: out has no reuse; keep L2/L3 for x (native vec type req'd)
    __builtin_nontemporal_store(o, (f32x4*)(out + rowbase + (size_t)t * ND + 4 * l));
    xv = xn;
  }
}

extern "C" void kernel_launch(void* const* d_in, const int* in_sizes, int n_in,
                              void* d_out, int out_size, void* d_ws, size_t ws_size,
                              hipStream_t stream) {
  const float* x = (const float*)d_in[0];
  const float* A = (const float*)d_in[1];
  const float* Bm = (const float*)d_in[2];
  const float* Cm = (const float*)d_in[3];
  const float* Dv = (const float*)d_in[4];
  const float* gamma = (const float*)d_in[5];
  const float* beta = (const float*)d_in[6];
  float* out = (float*)d_out;
  char* ws = (char*)d_ws;

  float* carry = (float*)ws;         // 64 KiB
  float* vws = (float*)(ws + 65536); // 4 MiB

  k_carry<<<dim3(NB * NCH), dim3(256), 0, stream>>>(x, A, Bm, carry, vws);
  k_out<<<dim3(NB * NCH), dim3(256), 0, stream>>>(x, A, Cm, Dv, gamma, beta,
                                                  carry, vws, out);
}

// Round 5
// 144.922 us; speedup vs baseline: 1.1603x; 1.0624x over previous
//
#include <hip/hip_runtime.h>
#include <math.h>

// S4 layer: B=16, S=4096, D=256, N=16, then LayerNorm over D.
//   A_d = exp(-DT*|A|), v_t = DT*(Bm @ u_t)
//   h_t = clip(A_d*h_{t-1} + v_t); y_t = clip(h_t @ Cm^T + u_t*Dv); out = LN(y)
// Chunked linear scan (chunks of 64 tokens), 2 dispatches:
//   k_carry: per (b,chunk): v via bf16 MFMA (store to ws) + chunk carry
//   k_out:   per (b,chunk): Hstart from carries, Kogge-Stone weighted scan in
//            LDS, y + LayerNorm, nontemporal store.
// R5: k_carry matvec -> mfma_f32_16x16x32_bf16 (M=64,N=16,K=256 GEMM).
//   bf16 input rounding perturbs final out by ~3e-7 (y is u*Dv-dominated);
//   kills the 4x ds_read_b128 B-broadcast per j (was ~50% of k_carry) and the
//   part2 cross-wave reduction (K-reduce is inside MFMA). LDS 55->42.5 KB ->
//   3 blocks/CU. Layouts (guide-measured): A[m=lane&15][k=quad*8+j],
//   B[k=quad*8+j][n=lane&15], C/D col=lane&15 row=quad*4+reg.

#define NB 16
#define NS 4096
#define ND 256
#define NN 16
#define NL 64
#define NCH 64 // NS / NL
#define DTC 1e-4f
#define XBSTR 264 // bf16 x-tile row stride (256+8): frag b128 reads 2-way (free)
#define BBSTR 264 // bf16 B-tile row stride
#define SCSTR 20  // scan LDS stride (80B rows, 16B-aligned for b128 broadcast)
#define NPOW (NL + 1)

typedef float f32x4 __attribute__((ext_vector_type(4)));
typedef short s16x8 __attribute__((ext_vector_type(8)));
typedef short s16x4 __attribute__((ext_vector_type(4)));

__device__ __forceinline__ float clip10(float v) { return fminf(fmaxf(v, -10.f), 10.f); }

__device__ __forceinline__ short f2bf(float f) { // fp32 -> bf16 (RNE)
  unsigned u = __float_as_uint(f);
  u += 0x7FFFu + ((u >> 16) & 1u);
  return (short)(u >> 16);
}

__global__ __launch_bounds__(256, 3) void k_carry(const float* __restrict__ x,
                                                  const float* __restrict__ A,
                                                  const float* __restrict__ Bm,
                                                  float* __restrict__ carry,
                                                  float* __restrict__ vws) {
  __shared__ __align__(16) short xtb[NL * XBSTR]; // 33 KB: bf16 x-tile [t][d]
  __shared__ __align__(16) short btb[NN * BBSTR]; // 8.25 KB: bf16 DT*Bm [n][d]
  __shared__ float part3[4][NN];
  const int tid = threadIdx.x;
  const int blk = blockIdx.x;
  const int b = blk >> 6, c = blk & 63;

  // Stage DT*Bm -> btb[n][d] (coalesced f4 reads, b64 LDS writes)
  const float4* Bm4 = (const float4*)Bm;
#pragma unroll
  for (int k = 0; k < 4; ++k) {
    int idx = tid + 256 * k; // f4 index, 1024 total
    int n = idx >> 6, d4 = idx & 63;
    float4 bv = Bm4[idx];
    s16x4 p = {f2bf(DTC * bv.x), f2bf(DTC * bv.y), f2bf(DTC * bv.z), f2bf(DTC * bv.w)};
    *(s16x4*)(btb + n * BBSTR + 4 * d4) = p;
  }
  // Stage x tile -> xtb[t][d] (coalesced f4 reads, b64 LDS writes, 2-way banks)
  const float4* xg4 = (const float4*)(x + ((size_t)(b * NS + c * NL)) * ND);
#pragma unroll
  for (int k = 0; k < 16; ++k) {
    int idx = tid + 256 * k; // f4 index, 4096 total (64 rows x 64 f4)
    int r = idx >> 6, q = idx & 63;
    float4 xv = xg4[idx];
    s16x4 p = {f2bf(xv.x), f2bf(xv.y), f2bf(xv.z), f2bf(xv.w)};
    *(s16x4*)(xtb + r * XBSTR + 4 * q) = p;
  }
  __syncthreads();

  const int l15 = tid & 15;
  const int quad = (tid & 63) >> 4;
  const int w = __builtin_amdgcn_readfirstlane(tid >> 6); // wave = 16-token tile

  // B fragments (shared across waves' tiles): B[k=quad*8+j][n=l15]
  s16x8 bfrag[8];
#pragma unroll
  for (int kk = 0; kk < 8; ++kk)
    bfrag[kk] = *(const s16x8*)(btb + l15 * BBSTR + kk * 32 + quad * 8);

  // v[t][n] = sum_d u[t][d] * (DT*Bm)[n][d]; K=256 in 8 MFMA steps
  f32x4 acc = {0.f, 0.f, 0.f, 0.f};
  const short* arow = xtb + (16 * w + l15) * XBSTR + quad * 8; // A[m=l15][k]
#pragma unroll
  for (int kk = 0; kk < 8; ++kk) {
    s16x8 af = *(const s16x8*)(arow + kk * 32);
    acc = __builtin_amdgcn_mfma_f32_16x16x32_bf16(af, bfrag[kk], acc, 0, 0, 0);
  }
  // lane holds v[t][n]: t = 16w + 4*quad + r, n = l15
  float* vp = vws + (size_t)blk * (NL * NN);
#pragma unroll
  for (int r = 0; r < 4; ++r)
    vp[(16 * w + 4 * quad + r) * NN + l15] = acc[r];

  // carry[n] = sum_t A_d[n]^(63-t) * v[t][n]
  const float pn = DTC * fabsf(A[l15]);
  float val = 0.f;
#pragma unroll
  for (int r = 0; r < 4; ++r) {
    int t = 16 * w + 4 * quad + r;
    val = fmaf(expf(-pn * (float)(63 - t)), acc[r], val);
  }
  val += __shfl_xor(val, 16); // sum over quads
  val += __shfl_xor(val, 32);
  if ((tid & 63) < NN) part3[w][l15] = val;
  __syncthreads();
  if (tid < NN)
    carry[(size_t)(b * NCH + c) * NN + tid] =
        (part3[0][tid] + part3[1][tid]) + (part3[2][tid] + part3[3][tid]);
}

__global__ __launch_bounds__(256, 4) void k_out(const float* __restrict__ x,
                                                const float* __restrict__ A,
                                                const float* __restrict__ Cm,
                                                const float* __restrict__ Dv,
                                                const float* __restrict__ gamma,
                                                const float* __restrict__ beta,
                                                const float* __restrict__ carry,
                                                const float* __restrict__ vws,
                                                float* __restrict__ out) {
  __shared__ __align__(16) float scan[NL * SCSTR];
  __shared__ float Ptab[NN * NPOW]; // Ptab[n][k] = A_d[n]^k
  __shared__ float hst[NN];
  __shared__ float part3[4][NN];
  const int tid = threadIdx.x;
  const int blk = blockIdx.x;
  const int b = blk >> 6, c = blk & 63;

  if (tid < NN) {
    float ad = expf(-DTC * fabsf(A[tid]));
    float p = 1.f;
    for (int k = 0; k < NPOW; ++k) { Ptab[tid * NPOW + k] = p; p *= ad; }
  }
  const float* vp = vws + (size_t)blk * (NL * NN);
#pragma unroll
  for (int k = 0; k < 4; ++k) {
    int e = tid + 256 * k;
    scan[(e >> 4) * SCSTR + (e & 15)] = vp[e];
  }

  // Hstart[n] = sum_{c'<c} (A_d^64)^(c-1-c') * carry[b][c'][n]
  {
    const int tt = tid >> 4, n = tid & 15;
    const float pn64 = 64.f * DTC * fabsf(A[n]);
    const float* cp = carry + (size_t)b * (NCH * NN);
    float val = 0.f;
#pragma unroll
    for (int q = 0; q < 4; ++q) {
      int cc = tt + 16 * q;
      if (cc < c) val = fmaf(expf(-pn64 * (float)(c - 1 - cc)), cp[cc * NN + n], val);
    }
    val += __shfl_xor(val, 16);
    val += __shfl_xor(val, 32);
    const int w = tid >> 6, lane = tid & 63;
    if (lane < NN) part3[w][lane] = val;
  }
  __syncthreads(); // scan + Ptab + part3 ready
  if (tid < NN)
    hst[tid] = (part3[0][tid] + part3[1][tid]) + (part3[2][tid] + part3[3][tid]);
  __syncthreads();

  // Kogge-Stone inclusive scan over t (per n) with decay weights A^s
#pragma unroll
  for (int s = 1; s <= 32; s <<= 1) {
    float tmp[4];
#pragma unroll
    for (int k = 0; k < 4; ++k) {
      int e = tid + 256 * k;
      int tt = e >> 4, n = e & 15;
      tmp[k] = (tt >= s) ? Ptab[n * NPOW + s] * scan[(tt - s) * SCSTR + n] : 0.f;
    }
    __syncthreads();
#pragma unroll
    for (int k = 0; k < 4; ++k) {
      int e = tid + 256 * k;
      scan[(e >> 4) * SCSTR + (e & 15)] += tmp[k];
    }
    __syncthreads();
  }
  // h_t = A^(tl+1) * Hstart + hloc_t, clip (no-op on this data, matches ref)
#pragma unroll
  for (int k = 0; k < 4; ++k) {
    int e = tid + 256 * k;
    int tt = e >> 4, n = e & 15;
    float hv = fmaf(Ptab[n * NPOW + tt + 1], hst[n], scan[tt * SCSTR + n]);
    scan[tt * SCSTR + n] = clip10(hv);
  }
  __syncthreads();

  // y = h @ Cm^T + u*Dv, clip, LayerNorm over d (d = lane dim -> wave butterfly)
  const int l = tid & 63;
  const int w = __builtin_amdgcn_readfirstlane(tid >> 6);
  float cm[4][NN]; // Cm rows for this lane's 4 d's, hoisted
  const float4* Cm4 = (const float4*)Cm;
#pragma unroll
  for (int j = 0; j < 4; ++j)
#pragma unroll
    for (int q = 0; q < 4; ++q) {
      float4 cv = Cm4[(4 * l + j) * 4 + q];
      cm[j][4 * q + 0] = cv.x; cm[j][4 * q + 1] = cv.y;
      cm[j][4 * q + 2] = cv.z; cm[j][4 * q + 3] = cv.w;
    }
  const float4 dv = ((const float4*)Dv)[l];
  const float4 gm = ((const float4*)gamma)[l];
  const float4 bet = ((const float4*)beta)[l];
  const size_t rowbase = ((size_t)(b * NS + c * NL)) * ND;
  const float* xbase = x + rowbase + 4 * l;

  float4 xv = *(const float4*)(xbase + (size_t)(16 * w) * ND); // prefetch t=16w
#pragma unroll 1
  for (int it = 0; it < 16; ++it) { // wave w handles tokens [16w, 16w+16)
    const int t = 16 * w + it;
    const int tn = (it < 15) ? (t + 1) : t;
    float4 xn = *(const float4*)(xbase + (size_t)tn * ND); // prefetch next token
    const float* hrow = scan + t * SCSTR; // 16B-aligned uniform b128 broadcasts
    float y0 = xv.x * dv.x, y1 = xv.y * dv.y, y2 = xv.z * dv.z, y3 = xv.w * dv.w;
#pragma unroll
    for (int nn = 0; nn < NN; ++nn) {
      float hv = hrow[nn];
      y0 = fmaf(hv, cm[0][nn], y0);
      y1 = fmaf(hv, cm[1][nn], y1);
      y2 = fmaf(hv, cm[2][nn], y2);
      y3 = fmaf(hv, cm[3][nn], y3);
    }
    y0 = clip10(y0); y1 = clip10(y1); y2 = clip10(y2); y3 = clip10(y3);
    float s1 = (y0 + y1) + (y2 + y3);
    float s2 = fmaf(y0, y0, fmaf(y1, y1, fmaf(y2, y2, y3 * y3)));
#pragma unroll
    for (int off = 32; off; off >>= 1) {
      s1 += __shfl_xor(s1, off);
      s2 += __shfl_xor(s2, off);
    }
    const float mu = s1 * (1.f / 256.f);
    const float var = fmaf(-mu, mu, s2 * (1.f / 256.f));
    const float rs = rsqrtf(var + 1e-5f);
    f32x4 o;
    o.x = fmaf((y0 - mu) * rs, gm.x, bet.x);
    o.y = fmaf((y1 - mu) * rs, gm.y, bet.y);
    o.z = fmaf((y2 - mu) * rs, gm.z, bet.z);
    o.w = fmaf((y3 - mu) * rs, gm.w, bet.w);
    // nontemporal: out has no reuse; keep L2/L3 for x
    __builtin_nontemporal_store(o, (f32x4*)(out + rowbase + (size_t)t * ND + 4 * l));
    xv = xn;
  }
}

extern "C" void kernel_launch(void* const* d_in, const int* in_sizes, int n_in,
                              void* d_out, int out_size, void* d_ws, size_t ws_size,
                              hipStream_t stream) {
  const float* x = (const float*)d_in[0];
  const float* A = (const float*)d_in[1];
  const float* Bm = (const float*)d_in[2];
  const float* Cm = (const float*)d_in[3];
  const float* Dv = (const float*)d_in[4];
  const float* gamma = (const float*)d_in[5];
  const float* beta = (const float*)d_in[6];
  float* out = (float*)d_out;
  char* ws = (char*)d_ws;

  float* carry = (float*)ws;         // 64 KiB
  float* vws = (float*)(ws + 65536); // 4 MiB

  k_carry<<<dim3(NB * NCH), dim3(256), 0, stream>>>(x, A, Bm, carry, vws);
  k_out<<<dim3(NB * NCH), dim3(256), 0, stream>>>(x, A, Cm, Dv, gamma, beta,
                                                  carry, vws, out);
}